// Round 5
// baseline (122.971 us; speedup 1.0000x reference)
//
#include <hip/hip_runtime.h>
#include <hip/hip_fp16.h>

// FlowAlignedSmoothingEffect — round 5.
// R4 post-mortem: 50us kernel, VALUBusy 66% (~33us of VALU issue), LDS ~15us,
// HBM 83MB fetch (2.85x halo over-fetch). Now VALU-bound.
// Changes:
//  - 32x32 tile, 4 px/thread: halo over-fetch 2.85x -> 1.8x, staging amortized.
//  - x stored as f16 (pk cvt, 2 instr/record vs 13 for sw-bf16; err 5e-4).
//  - interior/border template split: interior blocks (1924/2048) skip all
//    clamps and the in-bounds test (positions provably stay inside).
//  - center x/tangent read from own LDS slot (tangent exact f32 preserved
//    for the vt<0 flip chain).
// Window bound: |tf|<1 (convex blend of unit vectors), <=3 live steps
// (sigma<6 => half_width<12, r=3,6,9) + 1 initial offset => taps within
// [-3,+4] px; halo 5/6 leaves 2 px slack. NWIN=43, 1849 recs * 16B = 29.6KB.

#define HH 1024
#define WW 1024
#define CC 3
#define BB 2
#define NPIX (HH * WW)

#define TS 32
#define HALO_LO 5
#define NWIN 43                 // 32 + 5 + 6
#define NREC (NWIN * NWIN)      // 1849

__device__ __forceinline__ unsigned pk_f16x2(float a, float b) {
    __half2 h = __floats2half2_rn(a, b);
    return *(const unsigned*)&h;
}
__device__ __forceinline__ float2 unpk_f16x2(unsigned u) {
    __half2 h = *(const __half2*)&u;
    return __half22float2(h);
}

template <bool BORDER>
__device__ __forceinline__ float4 march_pixel(
    const uint4* __restrict__ win, int win_x0, int win_y0,
    int ix, int iy, float t0x, float t0y,
    float half_width, float inv_two_sigma2, float step)
{
    const float invT = 1.0f / 1024.0f;
    float acc0 = 0.f, acc1 = 0.f, acc2 = 0.f, accs = 0.f;

    float vx[2], vy[2], px[2], py[2];
    vx[0] = t0x;  vy[0] = t0y;
    vx[1] = -t0x; vy[1] = -t0y;
    const float p0x = ((float)ix + 0.5f) * invT;
    const float p0y = ((float)iy + 0.5f) * invT;
    px[0] = p0x + vx[0] * invT;  py[0] = p0y + vy[0] * invT;
    px[1] = p0x + vx[1] * invT;  py[1] = p0y + vy[1] * invT;

    float r = step;
    for (int it = 0; it < 8; ++it) {
        if (!(r < half_width)) break;          // uniform per batch
        const float k = __expf(-r * r * inv_two_sigma2);

        #pragma unroll
        for (int c = 0; c < 2; ++c) {
            const float fx = px[c] * 1024.0f - 0.5f;
            const float fy = py[c] * 1024.0f - 0.5f;
            const float x0f = floorf(fx);
            const float y0f = floorf(fy);
            const float wx = fx - x0f;         // weights from UNclamped floor
            const float wy = fy - y0f;

            int jx0, jx1, jy0, jy1;
            if (BORDER) {
                int x0i = (int)x0f, y0i = (int)y0f;
                x0i = min(max(x0i, 0), WW - 1);
                y0i = min(max(y0i, 0), HH - 1);
                const int x1i = min(x0i + 1, WW - 1);
                const int y1i = min(y0i + 1, HH - 1);
                jx0 = x0i - win_x0; jx1 = x1i - win_x0;
                jy0 = y0i - win_y0; jy1 = y1i - win_y0;
            } else {
                jx0 = (int)x0f - win_x0; jx1 = jx0 + 1;
                jy0 = (int)y0f - win_y0; jy1 = jy0 + 1;
            }

            const uint4 q00 = win[jy0 * NWIN + jx0];
            const uint4 q01 = win[jy0 * NWIN + jx1];
            const uint4 q10 = win[jy1 * NWIN + jx0];
            const uint4 q11 = win[jy1 * NWIN + jx1];

            const float wxm = 1.f - wx;
            const float wym = 1.f - wy;
            const float w00 = wxm * wym, w01 = wx * wym;
            const float w10 = wxm * wy,  w11 = wx * wy;

            float tfx = __uint_as_float(q00.x) * w00 + __uint_as_float(q01.x) * w01
                      + __uint_as_float(q10.x) * w10 + __uint_as_float(q11.x) * w11;
            float tfy = __uint_as_float(q00.y) * w00 + __uint_as_float(q01.y) * w01
                      + __uint_as_float(q10.y) * w10 + __uint_as_float(q11.y) * w11;

            bool inb = true;
            if (BORDER)
                inb = (px[c] >= 0.f) && (px[c] < 1.f) &&
                      (py[c] >= 0.f) && (py[c] < 1.f);
            if (inb) {
                const float2 a00 = unpk_f16x2(q00.z);
                const float2 a01 = unpk_f16x2(q01.z);
                const float2 a10 = unpk_f16x2(q10.z);
                const float2 a11 = unpk_f16x2(q11.z);
                const float2 b00 = unpk_f16x2(q00.w);
                const float2 b01 = unpk_f16x2(q01.w);
                const float2 b10 = unpk_f16x2(q10.w);
                const float2 b11 = unpk_f16x2(q11.w);
                acc0 += k * (a00.x * w00 + a01.x * w01 + a10.x * w10 + a11.x * w11);
                acc1 += k * (a00.y * w00 + a01.y * w01 + a10.y * w10 + a11.y * w11);
                acc2 += k * (b00.x * w00 + b01.x * w01 + b10.x * w10 + b11.x * w11);
                accs += k;
            }

            const float vt = vx[c] * tfx + vy[c] * tfy;
            if (vt < 0.f) { tfx = -tfx; tfy = -tfy; }
            vx[c] = tfx; vy[c] = tfy;
            px[c] += tfx * invT;
            py[c] += tfy * invT;
        }
        r += step;
    }
    return make_float4(acc0, acc1, acc2, accs);
}

__global__ __launch_bounds__(256) void flow_smooth_lds32(
    const float* __restrict__ x, const float* __restrict__ tng,
    const float* __restrict__ sigma, float* __restrict__ out)
{
    __shared__ uint4 win[NREC];   // 29584 B

    const int b = blockIdx.z;
    const int tile_x0 = blockIdx.x * TS;
    const int tile_y0 = blockIdx.y * TS;
    const int win_x0 = tile_x0 - HALO_LO;
    const int win_y0 = tile_y0 - HALO_LO;

    const float* __restrict__ xb  = x   + (size_t)b * CC * NPIX;
    const float* __restrict__ tbx = tng + (size_t)b * 2 * NPIX;
    const float* __restrict__ tby = tbx + NPIX;

    // ---- stage 43x43 window (clamped-replicated; coalesced row segments) ----
    for (int j = threadIdx.x; j < NREC; j += 256) {
        const int jy = j / NWIN;
        const int jx = j - jy * NWIN;
        const int gy = min(max(win_y0 + jy, 0), HH - 1);
        const int gx = min(max(win_x0 + jx, 0), WW - 1);
        const int g  = gy * WW + gx;
        uint4 rec;
        rec.x = __float_as_uint(tbx[g]);
        rec.y = __float_as_uint(tby[g]);
        rec.z = pk_f16x2(xb[g], xb[NPIX + g]);
        rec.w = pk_f16x2(xb[2 * NPIX + g], 0.0f);
        win[j] = rec;
    }
    __syncthreads();

    const float sig = sigma[b];
    const float half_width = 2.0f * sig;
    const float inv_two_sigma2 = 1.0f / (2.0f * sig * sig);
    const float step = (float)(1.0 / 0.3333);

    const int tx  = threadIdx.x & 31;
    const int ty0 = threadIdx.x >> 5;
    float* __restrict__ ob = out + (size_t)b * CC * NPIX;

    const bool border = (blockIdx.x == 0) | (blockIdx.x == gridDim.x - 1) |
                        (blockIdx.y == 0) | (blockIdx.y == gridDim.y - 1);

    if (!border) {
        #pragma unroll
        for (int q = 0; q < 4; ++q) {
            const int ly = ty0 + 8 * q;
            const int ix = tile_x0 + tx;
            const int iy = tile_y0 + ly;
            const uint4 own = win[(ly + HALO_LO) * NWIN + (tx + HALO_LO)];
            const float t0x = __uint_as_float(own.x);
            const float t0y = __uint_as_float(own.y);
            const float2 c01 = unpk_f16x2(own.z);
            const float2 c2p = unpk_f16x2(own.w);
            const float4 a = march_pixel<false>(win, win_x0, win_y0, ix, iy,
                                                t0x, t0y, half_width,
                                                inv_two_sigma2, step);
            const float inv_den = 1.0f / (1.0f + a.w);
            const int pix = iy * WW + ix;
            ob[pix]            = (c01.x + a.x) * inv_den;
            ob[NPIX + pix]     = (c01.y + a.y) * inv_den;
            ob[2 * NPIX + pix] = (c2p.x + a.z) * inv_den;
        }
    } else {
        #pragma unroll
        for (int q = 0; q < 4; ++q) {
            const int ly = ty0 + 8 * q;
            const int ix = tile_x0 + tx;
            const int iy = tile_y0 + ly;
            const uint4 own = win[(ly + HALO_LO) * NWIN + (tx + HALO_LO)];
            const float t0x = __uint_as_float(own.x);
            const float t0y = __uint_as_float(own.y);
            const float2 c01 = unpk_f16x2(own.z);
            const float2 c2p = unpk_f16x2(own.w);
            const float4 a = march_pixel<true>(win, win_x0, win_y0, ix, iy,
                                               t0x, t0y, half_width,
                                               inv_two_sigma2, step);
            const float inv_den = 1.0f / (1.0f + a.w);
            const int pix = iy * WW + ix;
            ob[pix]            = (c01.x + a.x) * inv_den;
            ob[NPIX + pix]     = (c01.y + a.y) * inv_den;
            ob[2 * NPIX + pix] = (c2p.x + a.z) * inv_den;
        }
    }
}

extern "C" void kernel_launch(void* const* d_in, const int* in_sizes, int n_in,
                              void* d_out, int out_size, void* d_ws, size_t ws_size,
                              hipStream_t stream) {
    const float* x  = (const float*)d_in[0];
    const float* t  = (const float*)d_in[1];
    const float* sg = (const float*)d_in[2];
    float* out = (float*)d_out;

    dim3 grid(WW / TS, HH / TS, BB);
    flow_smooth_lds32<<<grid, dim3(256), 0, stream>>>(x, t, sg, out);
}